// Round 9
// baseline (66.498 us; speedup 1.0000x reference)
//
#include <hip/hip_runtime.h>
#include <hip/hip_bf16.h>
#include <math.h>

#define BATCH 256
#define DM    768
#define REPR  1024
#define FF    3072

typedef __attribute__((ext_vector_type(8))) short bf16x8;
typedef __attribute__((ext_vector_type(4))) float f32x4;

__device__ __forceinline__ unsigned bf16rne(float f){
  union{float f; unsigned u;} x; x.f = f;
  return (x.u + 0x7FFFu + ((x.u >> 16) & 1u)) >> 16;
}
__device__ __forceinline__ unsigned pk2(float lo, float hi){
  return bf16rne(lo) | (bf16rne(hi) << 16);
}

// ---------------------------------------------------------------------------
// K1 prep_g1: two independent block families in one kernel.
//  ids [0,96):     G1 UNSPLIT (M=256,N=768,K=1024): x = im @ Wv2 + bv2,
//                  epilogue writes xf (f32) + xbf (bf16) directly. B read
//                  straight from raw f32 Wv2 (read exactly once, no transpose).
//                  r5 showed unsplit-G1 alone starves (96 blocks); here the
//                  1152 transpose blocks co-resident supply the TLP.
//  ids [96,1248):  W1/W2 transpose+convert f32[K][N] -> bf16[N][K], 64x64 tiles.
// ---------------------------------------------------------------------------
__global__ __launch_bounds__(256)
void prep_g1(const float* __restrict__ Wv2, const float* __restrict__ W1,
             const float* __restrict__ W2, const float* __restrict__ im,
             const float* __restrict__ bv2,
             ushort* __restrict__ W1t, ushort* __restrict__ W2t,
             float* __restrict__ xf, ushort* __restrict__ xbf)
{
  const int id = blockIdx.x, tid = threadIdx.x;

  if (id < 96) {                         // ---- G1 blocks (unsplit K) ----
    const int bx = id % 12, by = id / 12;
    const int lane = tid & 63, wid = tid >> 6;
    const int wr = wid >> 1, wc = wid & 1;
    const int arow = by * 32 + wr * 16 + (lane & 15);
    const int colb = bx * 64 + wc * 32;
    const int kq8  = (lane >> 4) * 8;

    const float* apf  = im + (size_t)arow * REPR + kq8;
    const int c0 = colb + (lane & 15), c1 = c0 + 16;
    const float* wrow = Wv2 + (size_t)kq8 * DM;

    f32x4 acc0 = (f32x4)(0.0f), acc1 = (f32x4)(0.0f);

    float4 a0c = *(const float4*)apf, a1c = *(const float4*)(apf + 4);
    float b0c[8], b1c[8];
    #pragma unroll
    for (int j = 0; j < 8; ++j) {
      b0c[j] = wrow[(size_t)j * DM + c0];
      b1c[j] = wrow[(size_t)j * DM + c1];
    }

    for (int s = 0; s < 32; ++s) {       // 32 K-steps, depth-1 prefetch
      float4 a0n, a1n; float b0n[8], b1n[8];
      const bool more = (s + 1) < 32;
      if (more) {
        const float* a2 = apf + (s + 1) * 32;
        a0n = *(const float4*)a2; a1n = *(const float4*)(a2 + 4);
        const float* w2r = wrow + (size_t)(s + 1) * 32 * DM;
        #pragma unroll
        for (int j = 0; j < 8; ++j) {
          b0n[j] = w2r[(size_t)j * DM + c0];
          b1n[j] = w2r[(size_t)j * DM + c1];
        }
      }
      union U { unsigned u[4]; bf16x8 v; } afr, bfr0, bfr1;
      afr.u[0] = pk2(a0c.x, a0c.y); afr.u[1] = pk2(a0c.z, a0c.w);
      afr.u[2] = pk2(a1c.x, a1c.y); afr.u[3] = pk2(a1c.z, a1c.w);
      #pragma unroll
      for (int j = 0; j < 4; ++j) {
        bfr0.u[j] = pk2(b0c[2*j], b0c[2*j+1]);
        bfr1.u[j] = pk2(b1c[2*j], b1c[2*j+1]);
      }
      acc0 = __builtin_amdgcn_mfma_f32_16x16x32_bf16(afr.v, bfr0.v, acc0, 0, 0, 0);
      acc1 = __builtin_amdgcn_mfma_f32_16x16x32_bf16(afr.v, bfr1.v, acc1, 0, 0, 0);
      if (more) {
        a0c = a0n; a1c = a1n;
        #pragma unroll
        for (int j = 0; j < 8; ++j) { b0c[j] = b0n[j]; b1c[j] = b1n[j]; }
      }
    }

    const int crow = by * 32 + wr * 16 + (lane >> 4) * 4;
    #pragma unroll
    for (int nf = 0; nf < 2; ++nf) {
      const int c = colb + nf * 16 + (lane & 15);
      const f32x4 a = nf ? acc1 : acc0;
      const float bb = bv2[c];
      #pragma unroll
      for (int r = 0; r < 4; ++r) {
        const float v = a[r] + bb;
        xf [(size_t)(crow + r) * DM + c] = v;
        xbf[(size_t)(crow + r) * DM + c] = (ushort)bf16rne(v);
      }
    }
    return;
  }

  // ---- transpose blocks (W1, W2) ----
  const int rel0 = id - 96;
  const float* src; ushort* dst; int K, N, rel;
  if (rel0 < 576) { src = W1; dst = W1t; K = DM; N = FF; rel = rel0; }
  else            { src = W2; dst = W2t; K = FF; N = DM; rel = rel0 - 576; }
  const int ntk = K >> 6;
  const int k0 = (rel % ntk) * 64, n0 = (rel / ntk) * 64;

  __shared__ float lds[64][65];          // +1 pad: column reads 2-way (free)
  #pragma unroll
  for (int p = 0; p < 4; ++p) {
    const int r = p * 16 + (tid >> 4), c4 = (tid & 15) * 4;
    float4 v = *(const float4*)(src + (size_t)(k0 + r) * N + n0 + c4);
    lds[r][c4] = v.x; lds[r][c4+1] = v.y; lds[r][c4+2] = v.z; lds[r][c4+3] = v.w;
  }
  __syncthreads();
  #pragma unroll
  for (int p = 0; p < 4; ++p) {
    const int nn = p * 16 + (tid >> 4), k4 = (tid & 15) * 4;
    uint2 o = { pk2(lds[k4][nn], lds[k4+1][nn]),
                pk2(lds[k4+2][nn], lds[k4+3][nn]) };
    *(uint2*)(dst + (size_t)(n0 + nn) * K + k0 + k4) = o;
  }
}

// ---------------------------------------------------------------------------
// gemm_rr: r4-exact register-only GEMM. 32x64 block tile, 4 waves 2x2 (wave
// 16x32, 2 mfma/step, 3 x b128 loads/step), depth-1 prefetch, runtime nsteps.
// Frag map (r3/r4-verified): in row/col = lane&15, k-octet = lane>>4;
//                            out col = lane&15, row = (lane>>4)*4 + r.
// EPI 0: raw f32 partial -> outF[z][BATCH][N];  EPI 1: +bias, gelu -> bf16.
// ---------------------------------------------------------------------------
template<int EPI>
__global__ __launch_bounds__(256)
void gemm_rr(const ushort* __restrict__ Abf, const ushort* __restrict__ Bt,
             const float* __restrict__ bias, float* __restrict__ outF,
             ushort* __restrict__ outH, int N, int K, int lda, int kcount)
{
  const int gx = gridDim.x, gy = gridDim.y;
  const int nwg = gx * gy;
  int id = blockIdx.y * gx + blockIdx.x;
  if ((nwg & 7) == 0) id = (id & 7) * (nwg >> 3) + (id >> 3);  // XCD swizzle
  const int bx = id / gy, by = id % gy;

  const int lane = threadIdx.x & 63, wid = threadIdx.x >> 6;
  const int wr = wid >> 1, wc = wid & 1;
  const int arow = by * 32 + wr * 16 + (lane & 15);
  const int colb = bx * 64 + wc * 32;
  const int kq = (lane >> 4) * 8;
  const int kb = blockIdx.z * kcount;

  const ushort* ap  = Abf + (size_t)arow * lda + kb + kq;
  const ushort* bp0 = Bt + (size_t)(colb + (lane & 15)) * K + kb + kq;
  const ushort* bp1 = Bt + (size_t)(colb + 16 + (lane & 15)) * K + kb + kq;

  f32x4 acc0 = (f32x4)(0.0f), acc1 = (f32x4)(0.0f);
  const int nsteps = kcount >> 5;

  union U { uint4 q; bf16x8 v; };
  U a_c, b0_c, b1_c;
  a_c.q  = *(const uint4*)ap;
  b0_c.q = *(const uint4*)bp0;
  b1_c.q = *(const uint4*)bp1;

  for (int t = 0; t < nsteps; ++t) {
    U a_n, b0_n, b1_n;
    const bool more = (t + 1) < nsteps;
    if (more) {                          // issue next-step loads before MFMA
      a_n.q  = *(const uint4*)(ap  + (t + 1) * 32);
      b0_n.q = *(const uint4*)(bp0 + (t + 1) * 32);
      b1_n.q = *(const uint4*)(bp1 + (t + 1) * 32);
    }
    acc0 = __builtin_amdgcn_mfma_f32_16x16x32_bf16(a_c.v, b0_c.v, acc0, 0, 0, 0);
    acc1 = __builtin_amdgcn_mfma_f32_16x16x32_bf16(a_c.v, b1_c.v, acc1, 0, 0, 0);
    if (more) { a_c = a_n; b0_c = b0_n; b1_c = b1_n; }
  }

  const int crow = by * 32 + wr * 16 + (lane >> 4) * 4;
  #pragma unroll
  for (int nf = 0; nf < 2; ++nf) {
    const int c = colb + nf * 16 + (lane & 15);
    const f32x4 a = nf ? acc1 : acc0;
    #pragma unroll
    for (int r = 0; r < 4; ++r) {
      const int row = crow + r;
      if (EPI == 0) {
        outF[(size_t)blockIdx.z * BATCH * N + (size_t)row * N + c] = a[r];
      } else {
        float v = a[r] + bias[c];
        v = 0.5f * v * (1.0f + erff(v * 0.70710678118654752f));
        outH[(size_t)row * N + c] = (ushort)bf16rne(v);
      }
    }
  }
}

// ---------------------------------------------------------------------------
// K4 ln_final: y = xf + sum_{z<4} P3[z] + b2, LayerNorm -> out. 1 block/row.
// ---------------------------------------------------------------------------
__global__ __launch_bounds__(256)
void ln_final(const float* __restrict__ P3, const float* __restrict__ xf,
              const float* __restrict__ b2, const float* __restrict__ g,
              const float* __restrict__ be, float* __restrict__ out)
{
  const int row = blockIdx.x, tid = threadIdx.x;
  const int lane = tid & 63, wave = tid >> 6;

  float v[3];
  #pragma unroll
  for (int i = 0; i < 3; ++i) {
    const int c = tid + i * 256;
    float s = xf[(size_t)row * DM + c] + b2[c];
    #pragma unroll
    for (int z = 0; z < 4; ++z) s += P3[((size_t)z * BATCH + row) * DM + c];
    v[i] = s;
  }

  __shared__ float red[4];
  float s = v[0] + v[1] + v[2];
  #pragma unroll
  for (int o = 32; o > 0; o >>= 1) s += __shfl_down(s, o);
  if (lane == 0) red[wave] = s;
  __syncthreads();
  const float mu = (red[0] + red[1] + red[2] + red[3]) * (1.0f / 768.0f);
  __syncthreads();
  const float d0 = v[0] - mu, d1 = v[1] - mu, d2 = v[2] - mu;
  float q = d0*d0 + d1*d1 + d2*d2;
  #pragma unroll
  for (int o = 32; o > 0; o >>= 1) q += __shfl_down(q, o);
  if (lane == 0) red[wave] = q;
  __syncthreads();
  const float var = (red[0] + red[1] + red[2] + red[3]) * (1.0f / 768.0f);
  const float inv = rsqrtf(var + 1e-12f);

  float* o = out + (size_t)row * DM;
  o[tid      ] = d0 * inv * g[tid      ] + be[tid      ];
  o[tid + 256] = d1 * inv * g[tid + 256] + be[tid + 256];
  o[tid + 512] = d2 * inv * g[tid + 512] + be[tid + 512];
}

// ---------------------------------------------------------------------------
// 4 kernels: [prep(W1,W2) + G1-unsplit -> xf,xbf] -> G2 -> G3 (split-4) -> LN.
// GEMM grids/schedules identical to the proven r4/r8 configs. ws ~14.6 MB.
// ---------------------------------------------------------------------------
extern "C" void kernel_launch(void* const* d_in, const int* in_sizes, int n_in,
                              void* d_out, int out_size, void* d_ws, size_t ws_size,
                              hipStream_t stream)
{
  const float* im  = (const float*)d_in[0];
  const float* Wv2 = (const float*)d_in[12];
  const float* bv2 = (const float*)d_in[13];
  const float* W1  = (const float*)d_in[14];
  const float* b1  = (const float*)d_in[15];
  const float* W2  = (const float*)d_in[16];
  const float* b2  = (const float*)d_in[17];
  const float* g   = (const float*)d_in[18];
  const float* be  = (const float*)d_in[19];
  float* out = (float*)d_out;

  char* w = (char*)d_ws;
  ushort* W1t = (ushort*)(w);                // 3072*768*2  = 4718592
  ushort* W2t = (ushort*)(w + 4718592);      // 768*3072*2  = 4718592
  ushort* xbf = (ushort*)(w + 9437184);      // 256*768*2   = 393216
  ushort* tbf = (ushort*)(w + 9830400);      // 256*3072*2  = 1572864
  float*  xf  = (float*) (w + 11403264);     // 256*768*4   = 786432
  float*  P3  = (float*) (w + 12189696);     // 4*256*768*4 = 3145728 -> 14.6MB

  // K1: W1/W2 transpose + G1 unsplit (x = im@Wv2 + bv2 -> xf,xbf)
  prep_g1<<<1248, 256, 0, stream>>>(Wv2, W1, W2, im, bv2, W1t, W2t, xf, xbf);
  // K2 G2: tbf = bf16(gelu(x @ W1 + b1))   (M=256,N=3072,K=768)
  gemm_rr<1><<<dim3(48, 8, 1), 256, 0, stream>>>(xbf, W1t, b1, nullptr, tbf,
                                                 FF, DM, DM, 768);
  // K3 G3: P3[z] = (t @ W2) K-slices       (M=256,N=768,K=3072, split-4)
  gemm_rr<0><<<dim3(12, 8, 4), 256, 0, stream>>>(tbf, W2t, nullptr, P3, nullptr,
                                                 DM, FF, FF, 768);
  // K4: LN(xf + sum P3 + b2) -> out
  ln_final<<<BATCH, 256, 0, stream>>>(P3, xf, b2, g, be, out);
}